// Round 1
// baseline (892.194 us; speedup 1.0000x reference)
//
#include <hip/hip_runtime.h>

// WeatherLSTM: 2-layer LSTM (B=4096,T=168,I=4,H=64) + MLP head (64->64 relu ->12).
// Design (round 1, correctness-first but structured for speed):
//  - One fused kernel; grid 256 blocks x 256 threads; block owns Btile=16 samples.
//  - Batch rows are independent -> block loops t=0..167 locally, no global sync.
//  - lane = unit u (tid&63), wave = sample-quad sq (tid>>6). Each lane keeps
//    4 gate accumulators x 4 samples (fp32), c-state in regs (fp32).
//  - Weights packed half2-over-K in LDS (96KB); h exchanged per step through a
//    small double-buffered LDS buffer as f16 pairs; v_dot2_f32_f16 does 2 MACs
//    per inst with fp32 accumulation (precision budget ~5e-4 rel per term).
//  - 2 __syncthreads per step (write h0new -> layer1 reads it; end-of-step).
//  - LDS ~104.5KB -> 1 block/CU, 4 waves (1/SIMD); distance-2 software prefetch
//    in the K-loops hides ds_read latency (~120cyc) since TLP is minimal.

typedef _Float16 v2h __attribute__((ext_vector_type(2)));

#define SMEM_BYTES 107008   // 32K (W0) + 64K (W1cat) + 8K (h bufs) + 2.5K pad (prefetch overread)
#define W0_OFF 0
#define W1_OFF 32768
#define HC_OFF 98304

__device__ __forceinline__ float rcp_(float x) {
#if __has_builtin(__builtin_amdgcn_rcpf)
  return __builtin_amdgcn_rcpf(x);
#else
  return 1.f / x;
#endif
}
__device__ __forceinline__ float sigm(float x) { return rcp_(1.f + __expf(-x)); }
__device__ __forceinline__ float tanh_(float x) { return 2.f * rcp_(1.f + __expf(-2.f * x)) - 1.f; }

__device__ __forceinline__ float dot2(int w, int h, float acc) {
#if __has_builtin(__builtin_amdgcn_fdot2)
  return __builtin_amdgcn_fdot2(__builtin_bit_cast(v2h, w),
                                __builtin_bit_cast(v2h, h), acc, false);
#else
  v2h a = __builtin_bit_cast(v2h, w), b = __builtin_bit_cast(v2h, h);
  return acc + (float)a.x * (float)b.x + (float)a.y * (float)b.y;
#endif
}

// acc[sample i][gate g] += dot2(W pair for gate g, H pair for sample i)
#define DOT16(W, H) do { \
  acc[0][0] = dot2((W).x, (H).x, acc[0][0]); \
  acc[0][1] = dot2((W).y, (H).x, acc[0][1]); \
  acc[0][2] = dot2((W).z, (H).x, acc[0][2]); \
  acc[0][3] = dot2((W).w, (H).x, acc[0][3]); \
  acc[1][0] = dot2((W).x, (H).y, acc[1][0]); \
  acc[1][1] = dot2((W).y, (H).y, acc[1][1]); \
  acc[1][2] = dot2((W).z, (H).y, acc[1][2]); \
  acc[1][3] = dot2((W).w, (H).y, acc[1][3]); \
  acc[2][0] = dot2((W).x, (H).z, acc[2][0]); \
  acc[2][1] = dot2((W).y, (H).z, acc[2][1]); \
  acc[2][2] = dot2((W).z, (H).z, acc[2][2]); \
  acc[2][3] = dot2((W).w, (H).z, acc[2][3]); \
  acc[3][0] = dot2((W).x, (H).w, acc[3][0]); \
  acc[3][1] = dot2((W).y, (H).w, acc[3][1]); \
  acc[3][2] = dot2((W).z, (H).w, acc[3][2]); \
  acc[3][3] = dot2((W).w, (H).w, acc[3][3]); \
} while (0)

// K-loop with distance-2 prefetch. Overreads up to index JP1+1 -> smem padded.
#define KLOOP(WB, HB, JP0, JP1) do { \
  int4 wa = (WB)[(JP0) * 64 + u]; \
  int4 ha = (HB)[(JP0) * 4 + sq]; \
  int4 wc = (WB)[((JP0) + 1) * 64 + u]; \
  int4 hc2 = (HB)[((JP0) + 1) * 4 + sq]; \
  for (int jp = (JP0); jp < (JP1); jp += 2) { \
    int4 wn1 = (WB)[(jp + 2) * 64 + u]; \
    int4 hn1 = (HB)[(jp + 2) * 4 + sq]; \
    int4 wn2 = (WB)[(jp + 3) * 64 + u]; \
    int4 hn2 = (HB)[(jp + 3) * 4 + sq]; \
    DOT16(wa, ha); \
    DOT16(wc, hc2); \
    wa = wn1; ha = hn1; wc = wn2; hc2 = hn2; \
  } \
} while (0)

extern "C" __global__ void __launch_bounds__(256, 1)
weather_lstm_fused(const float* __restrict__ x,
                   const float* __restrict__ Wih0, const float* __restrict__ Whh0,
                   const float* __restrict__ bih0, const float* __restrict__ bhh0,
                   const float* __restrict__ Wih1, const float* __restrict__ Whh1,
                   const float* __restrict__ bih1, const float* __restrict__ bhh1,
                   const float* __restrict__ W1, const float* __restrict__ b1,
                   const float* __restrict__ W2, const float* __restrict__ b2,
                   float* __restrict__ out)
{
  __shared__ __align__(16) unsigned char smem[SMEM_BYTES];
  const int tid = threadIdx.x;
  const int u  = tid & 63;   // hidden unit
  const int sq = tid >> 6;   // sample quad (also wave id)
  const int s0 = sq * 4;     // first local sample
  const int sg0 = blockIdx.x * 16 + s0;

  // ---- stage weights to LDS as half2 pairs over the K dim ----
  // W0 layout: [jp(32)][u(64)][g(4)] dwords; pair = (Whh0[g*64+u][2jp], [..][2jp+1])
  {
    v2h* w0 = (v2h*)(smem + W0_OFF);
    for (int idx = tid; idx < 8192; idx += 256) {
      int jp = idx >> 8, rem = idx & 255, uu = rem >> 2, g = rem & 3;
      int row = g * 64 + uu;
      v2h pk = { (_Float16)Whh0[row * 64 + 2 * jp], (_Float16)Whh0[row * 64 + 2 * jp + 1] };
      w0[idx] = pk;
    }
    // W1cat layout: [jp(64)][u(64)][g(4)]; jp<32 -> Wih1 cols, jp>=32 -> Whh1 cols
    v2h* w1 = (v2h*)(smem + W1_OFF);
    for (int idx = tid; idx < 16384; idx += 256) {
      int jp = idx >> 8, rem = idx & 255, uu = rem >> 2, g = rem & 3;
      int row = g * 64 + uu;
      const float* src = (jp < 32) ? (Wih1 + row * 64 + 2 * jp)
                                   : (Whh1 + row * 64 + 2 * (jp - 32));
      v2h pk = { (_Float16)src[0], (_Float16)src[1] };
      w1[idx] = pk;
    }
    // zero h exchange buffers (+pad): 2 bufs x 64 jp x 16 s dwords
    int* hz = (int*)(smem + HC_OFF);
    for (int idx = tid; idx < 2176; idx += 256) hz[idx] = 0;
  }

  // ---- per-thread constants ----
  float bias0[4], bias1[4], w0r[4][4];
#pragma unroll
  for (int g = 0; g < 4; g++) {
    int r = g * 64 + u;
    bias0[g] = bih0[r] + bhh0[r];
    bias1[g] = bih1[r] + bhh1[r];
#pragma unroll
    for (int i2 = 0; i2 < 4; i2++) w0r[g][i2] = Wih0[r * 4 + i2];
  }
  const float b1u = b1[u];

  float c0[4] = {0.f, 0.f, 0.f, 0.f}, c1[4] = {0.f, 0.f, 0.f, 0.f};
  float hl1[4] = {0.f, 0.f, 0.f, 0.f};

  __syncthreads();

  const int4* w0b = (const int4*)(smem + W0_OFF);
  const int4* w1b = (const int4*)(smem + W1_OFF);
  const int4* hcb = (const int4*)(smem + HC_OFF);
  _Float16* hph = (_Float16*)(smem + HC_OFF);

  float4 xv[4], xn[4];
#pragma unroll
  for (int i = 0; i < 4; i++)
    xv[i] = *(const float4*)(x + ((size_t)(sg0 + i) * 168) * 4);

  float acc[4][4];

  for (int t = 0; t < 168; t++) {
    const int pb = t & 1, nb = pb ^ 1;
    const int4* hp_p = hcb + pb * 256;
    const int4* hp_n = hcb + nb * 256;

    // ---------- layer 0 ----------
#pragma unroll
    for (int i = 0; i < 4; i++)
#pragma unroll
      for (int g = 0; g < 4; g++)
        acc[i][g] = bias0[g] + w0r[g][0] * xv[i].x + w0r[g][1] * xv[i].y
                  + w0r[g][2] * xv[i].z + w0r[g][3] * xv[i].w;

    KLOOP(w0b, hp_p, 0, 32);

#pragma unroll
    for (int i = 0; i < 4; i++) {
      float iv = sigm(acc[i][0]);
      float fv = sigm(acc[i][1]);
      float gv = tanh_(acc[i][2]);
      float ov = sigm(acc[i][3]);
      c0[i] = fv * c0[i] + iv * gv;
      float hn = ov * tanh_(c0[i]);
      // h0_new -> HC[nb], jp rows 0..31 (feeds layer1 now, layer0 next step)
      hph[(nb * 1024 + (u >> 1) * 16 + s0 + i) * 2 + (u & 1)] = (_Float16)hn;
    }
    __syncthreads();

    // prefetch next x while layer1 computes
    {
      int tn = t < 167 ? t + 1 : 167;
#pragma unroll
      for (int i = 0; i < 4; i++)
        xn[i] = *(const float4*)(x + ((size_t)(sg0 + i) * 168 + tn) * 4);
    }

    // ---------- layer 1 ----------
#pragma unroll
    for (int i = 0; i < 4; i++)
#pragma unroll
      for (int g = 0; g < 4; g++)
        acc[i][g] = bias1[g];

    KLOOP(w1b, hp_n, 0, 32);   // Wih1 * h0_new (fresh buffer)
    KLOOP(w1b, hp_p, 32, 64);  // Whh1 * h1_prev (old buffer, rows 32..63)

#pragma unroll
    for (int i = 0; i < 4; i++) {
      float iv = sigm(acc[i][0]);
      float fv = sigm(acc[i][1]);
      float gv = tanh_(acc[i][2]);
      float ov = sigm(acc[i][3]);
      c1[i] = fv * c1[i] + iv * gv;
      float hn = ov * tanh_(c1[i]);
      hl1[i] = hn;
      hph[(nb * 1024 + (32 + (u >> 1)) * 16 + s0 + i) * 2 + (u & 1)] = (_Float16)hn;
    }
    __syncthreads();

#pragma unroll
    for (int i = 0; i < 4; i++) xv[i] = xn[i];
  }

  // ---------- MLP head ----------
  // last __syncthreads of the loop guarantees weight LDS is dead; reuse it.
  float* fh = (float*)smem;            // [16][64] final h2
#pragma unroll
  for (int i = 0; i < 4; i++) fh[(s0 + i) * 64 + u] = hl1[i];
  __syncthreads();

  float za[4];
#pragma unroll
  for (int i = 0; i < 4; i++) za[i] = b1u;
  for (int j = 0; j < 64; j++) {
    float w = W1[u * 64 + j];
#pragma unroll
    for (int i = 0; i < 4; i++) za[i] += w * fh[(s0 + i) * 64 + j];
  }
  float* zl = (float*)(smem + 4096);   // [16][64] relu(z)
#pragma unroll
  for (int i = 0; i < 4; i++) zl[(s0 + i) * 64 + u] = fmaxf(za[i], 0.f);
  __syncthreads();

  if (tid < 192) {
    int s = tid / 12, o = tid - s * 12;
    float a = b2[o];
    for (int j = 0; j < 64; j++) a += W2[o * 64 + j] * zl[s * 64 + j];
    out[(blockIdx.x * 16 + s) * 12 + o] = a;
  }
}

extern "C" void kernel_launch(void* const* d_in, const int* in_sizes, int n_in,
                              void* d_out, int out_size, void* d_ws, size_t ws_size,
                              hipStream_t stream) {
  (void)in_sizes; (void)n_in; (void)d_ws; (void)ws_size; (void)out_size;
  const float* x    = (const float*)d_in[0];
  const float* Wih0 = (const float*)d_in[1];
  const float* Whh0 = (const float*)d_in[2];
  const float* bih0 = (const float*)d_in[3];
  const float* bhh0 = (const float*)d_in[4];
  const float* Wih1 = (const float*)d_in[5];
  const float* Whh1 = (const float*)d_in[6];
  const float* bih1 = (const float*)d_in[7];
  const float* bhh1 = (const float*)d_in[8];
  const float* W1   = (const float*)d_in[9];
  const float* b1   = (const float*)d_in[10];
  const float* W2   = (const float*)d_in[11];
  const float* b2   = (const float*)d_in[12];

  weather_lstm_fused<<<dim3(256), dim3(256), 0, stream>>>(
      x, Wih0, Whh0, bih0, bhh0, Wih1, Whh1, bih1, bhh1, W1, b1, W2, b2,
      (float*)d_out);
}

// Round 2
// 252.597 us; speedup vs baseline: 3.5321x; 3.5321x over previous
//
#include <hip/hip_runtime.h>

// WeatherLSTM round 2: MFMA-based. 2-layer LSTM (B=4096,T=168,I=4,H=64) + head.
//
// Structure:
//  - grid 256 blocks x 512 threads (8 waves). Block owns 16 samples, loops t.
//  - Per step compute G^T = W * h^T via mfma_f32_16x16x32_f16:
//      A = weight tile (VGPR-resident, loaded once), B = h^T from LDS.
//  - Row permutation inside each 16-row A tile: row = unit_local*4 + gate, so
//    each lane's 4 C/D regs (rows quad*4+reg) = the 4 gates of ONE unit for
//    ONE sample (col=lane&15) -> activations are lane-local, c-state in regs.
//  - Wave w owns units [w*8, w*8+8) as 2 M-tiles (units w*8+q and w*8+4+q).
//  - Layer0 K=96: [h0_prev(64) | x_t(4) | 0-pad(28)]; Wih0 lives in A-frag2
//    (zeros past k=68); x[t+1] staged into the pad bytes of the h0 buffer each
//    step by lanes 0..15. Layer1 K=128: [h0_new(64)|h1_prev(64)] as 4 frags.
//  - LDS: only h exchange buffers, double-buffered, row stride 208B
//    (16B-aligned; 52 dwords -> 20i mod 32 covers banks uniformly, b128 reads
//    conflict-free). Total 13.3KB. Head overlays the dead h buffers.
//  - MFMA A-layout A[m=lane&15][k=quad*8+j] (verified m120); B mirrors with
//    n=lane&15; C/D col=lane&15,row=quad*4+reg (verified m89/m91).

typedef _Float16 h8 __attribute__((ext_vector_type(8)));
typedef _Float16 h4 __attribute__((ext_vector_type(4)));
typedef float f4 __attribute__((ext_vector_type(4)));

#define ROWB 208
#define HBUF (16 * ROWB)        // 3328 B per buffer
#define H0_OFF 0                // h0[2]
#define H1_OFF (2 * HBUF)       // h1[2]
#define SMEM_TOTAL (4 * HBUF)   // 13312 B (head reuses 8KB of this)

__device__ __forceinline__ float rcp_(float x) {
#if __has_builtin(__builtin_amdgcn_rcpf)
  return __builtin_amdgcn_rcpf(x);
#else
  return 1.f / x;
#endif
}
__device__ __forceinline__ float sigm(float x) { return rcp_(1.f + __expf(-x)); }
__device__ __forceinline__ float tanh_(float x) { return 2.f * rcp_(1.f + __expf(-2.f * x)) - 1.f; }

__device__ __forceinline__ f4 mfma16(h8 a, h8 b, f4 c) {
  return __builtin_amdgcn_mfma_f32_16x16x32_f16(a, b, c, 0, 0, 0);
}

__device__ __forceinline__ h8 load_w8(const float* __restrict__ p) {
  h8 r;
#pragma unroll
  for (int j = 0; j < 8; j++) r[j] = (_Float16)p[j];
  return r;
}

extern "C" __global__ void __launch_bounds__(512, 2)
weather_lstm_mfma(const float* __restrict__ x,
                  const float* __restrict__ Wih0, const float* __restrict__ Whh0,
                  const float* __restrict__ bih0, const float* __restrict__ bhh0,
                  const float* __restrict__ Wih1, const float* __restrict__ Whh1,
                  const float* __restrict__ bih1, const float* __restrict__ bhh1,
                  const float* __restrict__ W1, const float* __restrict__ b1,
                  const float* __restrict__ W2, const float* __restrict__ b2,
                  float* __restrict__ out)
{
  __shared__ __align__(16) unsigned char smem[SMEM_TOTAL];
  const int tid  = threadIdx.x;
  const int lane = tid & 63;
  const int w    = tid >> 6;      // wave 0..7
  const int col  = lane & 15;     // sample index within block (B-frag n / C col)
  const int quad = lane >> 4;     // 0..3
  const int sB   = blockIdx.x * 16;

  // ---- A-frag row decode: m = lane&15 = unit_local*4 + gate ----
  const int g_  = col & 3;        // gate for A-loading
  const int ul_ = col >> 2;       // unit_local (0..3) for A-loading
  int arow[2];                    // global weight row for tile 0/1
  arow[0] = g_ * 64 + w * 8 + 0 + ul_;
  arow[1] = g_ * 64 + w * 8 + 4 + ul_;

  // ---- load weight A-frags into registers (once) ----
  h8 a0[2][3];          // layer0: Whh0 k0..31, k32..63, [Wih0|0] k64..95
  h8 a1i[2][2];         // layer1: Wih1 (B rows 0..63 = h0_new)
  h8 a1h[2][2];         // layer1: Whh1 (B rows 64..127 = h1_prev)
#pragma unroll
  for (int T = 0; T < 2; T++) {
    const int r = arow[T];
#pragma unroll
    for (int f = 0; f < 2; f++) {
      a0[T][f]  = load_w8(Whh0 + r * 64 + f * 32 + quad * 8);
      a1i[T][f] = load_w8(Wih1 + r * 64 + f * 32 + quad * 8);
      a1h[T][f] = load_w8(Whh1 + r * 64 + f * 32 + quad * 8);
    }
    h8 xw = {};  // k=64..95: Wih0 cols 0..3 at quad==0, else zero
    if (quad == 0) {
#pragma unroll
      for (int j = 0; j < 4; j++) xw[j] = (_Float16)Wih0[r * 4 + j];
    }
    a0[T][2] = xw;
  }

  // ---- biases: lane's C rows quad*4+reg -> unit_local=quad, gate=reg ----
  f4 bias0v[2], bias1v[2];
#pragma unroll
  for (int T = 0; T < 2; T++) {
#pragma unroll
    for (int reg = 0; reg < 4; reg++) {
      const int rr = reg * 64 + w * 8 + T * 4 + quad;
      bias0v[T][reg] = bih0[rr] + bhh0[rr];
      bias1v[T][reg] = bih1[rr] + bhh1[rr];
    }
  }

  // ---- zero LDS (h buffers incl. pad), stage x[0] ----
  for (int idx = tid; idx < SMEM_TOTAL / 4; idx += 512) ((int*)smem)[idx] = 0;
  __syncthreads();
  if (tid < 16) {
    f4 xv = *(const f4*)(x + ((size_t)(sB + tid) * 168 + 0) * 4);
    h4 xh;
#pragma unroll
    for (int j = 0; j < 4; j++) xh[j] = (_Float16)xv[j];
    *(h4*)(smem + H0_OFF + 0 * HBUF + tid * ROWB + 128) = xh;
  }
  __syncthreads();

  float c0[2] = {0.f, 0.f}, c1[2] = {0.f, 0.f};
  float hl[2] = {0.f, 0.f};
  const int bo = col * ROWB + quad * 16;   // B-frag base byte offset in a buffer

  for (int t = 0; t < 168; t++) {
    const int pb = t & 1, nb = pb ^ 1;
    unsigned char* h0p = smem + H0_OFF + pb * HBUF;
    unsigned char* h0n = smem + H0_OFF + nb * HBUF;
    unsigned char* h1p = smem + H1_OFF + pb * HBUF;
    unsigned char* h1n = smem + H1_OFF + nb * HBUF;

    // stage x[t+1] into h0n pad bytes (read next step, after barrier2)
    if (tid < 16) {
      const int tn = (t < 167) ? t + 1 : 167;
      f4 xv = *(const f4*)(x + ((size_t)(sB + tid) * 168 + tn) * 4);
      h4 xh;
#pragma unroll
      for (int j = 0; j < 4; j++) xh[j] = (_Float16)xv[j];
      *(h4*)(h0n + tid * ROWB + 128) = xh;
    }

    // ---------- layer 0: G^T = [Whh0|Wih0|0] * [h0_prev|x|0]^T ----------
    h8 b0 = *(const h8*)(h0p + bo);         // k 0..31
    h8 b1v = *(const h8*)(h0p + bo + 64);   // k 32..63
    h8 b2v = *(const h8*)(h0p + bo + 128);  // k 64..95 (x + zero pad)

    f4 acc0 = bias0v[0], acc1 = bias0v[1];
    acc0 = mfma16(a0[0][0], b0, acc0);
    acc1 = mfma16(a0[1][0], b0, acc1);
    acc0 = mfma16(a0[0][1], b1v, acc0);
    acc1 = mfma16(a0[1][1], b1v, acc1);
    acc0 = mfma16(a0[0][2], b2v, acc0);
    acc1 = mfma16(a0[1][2], b2v, acc1);

#pragma unroll
    for (int T = 0; T < 2; T++) {
      f4 a = T ? acc1 : acc0;
      float iv = sigm(a[0]);
      float fv = sigm(a[1]);
      float gv = tanh_(a[2]);
      float ov = sigm(a[3]);
      c0[T] = fv * c0[T] + iv * gv;
      float hn = ov * tanh_(c0[T]);
      *(_Float16*)(h0n + col * ROWB + (w * 8 + T * 4 + quad) * 2) = (_Float16)hn;
    }
    __syncthreads();

    // ---------- layer 1: G^T = [Wih1|Whh1] * [h0_new|h1_prev]^T ----------
    h8 p0 = *(const h8*)(h0n + bo);
    h8 p1 = *(const h8*)(h0n + bo + 64);
    h8 q0 = *(const h8*)(h1p + bo);
    h8 q1 = *(const h8*)(h1p + bo + 64);

    acc0 = bias1v[0]; acc1 = bias1v[1];
    acc0 = mfma16(a1i[0][0], p0, acc0);
    acc1 = mfma16(a1i[1][0], p0, acc1);
    acc0 = mfma16(a1i[0][1], p1, acc0);
    acc1 = mfma16(a1i[1][1], p1, acc1);
    acc0 = mfma16(a1h[0][0], q0, acc0);
    acc1 = mfma16(a1h[1][0], q0, acc1);
    acc0 = mfma16(a1h[0][1], q1, acc0);
    acc1 = mfma16(a1h[1][1], q1, acc1);

#pragma unroll
    for (int T = 0; T < 2; T++) {
      f4 a = T ? acc1 : acc0;
      float iv = sigm(a[0]);
      float fv = sigm(a[1]);
      float gv = tanh_(a[2]);
      float ov = sigm(a[3]);
      c1[T] = fv * c1[T] + iv * gv;
      float hn = ov * tanh_(c1[T]);
      hl[T] = hn;
      *(_Float16*)(h1n + col * ROWB + (w * 8 + T * 4 + quad) * 2) = (_Float16)hn;
    }
    __syncthreads();
  }

  // ---------- MLP head (h buffers dead; overlay) ----------
  float* fh = (float*)smem;              // [16][64] final h2, fp32
#pragma unroll
  for (int T = 0; T < 2; T++)
    fh[col * 64 + (w * 8 + T * 4 + quad)] = hl[T];
  __syncthreads();

  {
    const int u = tid & 63, grp = tid >> 6;  // grp 0..7 -> 2 samples each
    float za0 = b1[u], za1 = b1[u];
    const float* w1r = W1 + u * 64;
    const float* f0 = fh + (grp * 2 + 0) * 64;
    const float* f1 = fh + (grp * 2 + 1) * 64;
    for (int j = 0; j < 64; j++) {
      float wv = w1r[j];
      za0 += wv * f0[j];
      za1 += wv * f1[j];
    }
    float* zl = (float*)(smem + 4096);     // [16][64]
    zl[(grp * 2 + 0) * 64 + u] = fmaxf(za0, 0.f);
    zl[(grp * 2 + 1) * 64 + u] = fmaxf(za1, 0.f);
  }
  __syncthreads();

  if (tid < 192) {
    const float* zl = (const float*)(smem + 4096);
    const int s = tid / 12, o = tid - s * 12;
    float a = b2[o];
    for (int j = 0; j < 64; j++) a += W2[o * 64 + j] * zl[s * 64 + j];
    out[(sB + s) * 12 + o] = a;
  }
}

extern "C" void kernel_launch(void* const* d_in, const int* in_sizes, int n_in,
                              void* d_out, int out_size, void* d_ws, size_t ws_size,
                              hipStream_t stream) {
  (void)in_sizes; (void)n_in; (void)d_ws; (void)ws_size; (void)out_size;
  const float* x    = (const float*)d_in[0];
  const float* Wih0 = (const float*)d_in[1];
  const float* Whh0 = (const float*)d_in[2];
  const float* bih0 = (const float*)d_in[3];
  const float* bhh0 = (const float*)d_in[4];
  const float* Wih1 = (const float*)d_in[5];
  const float* Whh1 = (const float*)d_in[6];
  const float* bih1 = (const float*)d_in[7];
  const float* bhh1 = (const float*)d_in[8];
  const float* W1   = (const float*)d_in[9];
  const float* b1   = (const float*)d_in[10];
  const float* W2   = (const float*)d_in[11];
  const float* b2   = (const float*)d_in[12];

  weather_lstm_mfma<<<dim3(256), dim3(512), 0, stream>>>(
      x, Wih0, Whh0, bih0, bhh0, Wih1, Whh1, bih1, bhh1, W1, b1, W2, b2,
      (float*)d_out);
}

// Round 3
// 233.262 us; speedup vs baseline: 3.8248x; 1.0829x over previous
//
#include <hip/hip_runtime.h>

// WeatherLSTM round 3: MFMA skeleton from R2 + VALU diet.
//  - grid 256 x 512 thr (8 waves); block owns 16 samples; wave owns 8 units.
//  - Tile T (T=0,1) covers units w*8 + 2*quad + T  (adjacent-unit mapping so
//    each thread's two h outputs pack into ONE ds_write_b32; bank pattern =
//    2 lanes/bank = conflict-free per m136).
//  - Weights/biases prescaled by log2e (i,f,o rows) / 2log2e (g rows) at load:
//      sigm(a) = rcp(1 + exp2(-a))          [3 insts, neg modifier free]
//      tanh(a) = 1 - 2*rcp(exp2(a) + 1)     [4 insts]
//    c-state kept in natural units; tanh(c) needs one extra mul by 2log2e.
//  - v_exp_f32 / v_rcp_f32 via builtins with inline-asm fallback (no libm).
//  - Layer1's Whh1*h1_prev MFMAs issued BEFORE barrier1 (h1_prev ready all
//    step) -> post-barrier chain = ds_read + 2 MFMA + activations only.
//  - MFMA layouts as verified (m89/m91/m120); LDS 13.3KB, h rows stride 208B.

typedef _Float16 h8 __attribute__((ext_vector_type(8)));
typedef _Float16 h4 __attribute__((ext_vector_type(4)));
typedef float f4 __attribute__((ext_vector_type(4)));

#define ROWB 208
#define HBUF (16 * ROWB)        // 3328 B per buffer
#define H0_OFF 0                // h0[2]
#define H1_OFF (2 * HBUF)       // h1[2]
#define SMEM_TOTAL (4 * HBUF)   // 13312 B

#define K1F 1.4426950408889634f   // log2(e)
#define K2F 2.8853900817779268f   // 2*log2(e)

__device__ __forceinline__ float exp2_(float x) {
#if __has_builtin(__builtin_amdgcn_exp2f)
  return __builtin_amdgcn_exp2f(x);
#else
  float r; asm("v_exp_f32 %0, %1" : "=v"(r) : "v"(x)); return r;
#endif
}
__device__ __forceinline__ float rcp_(float x) {
#if __has_builtin(__builtin_amdgcn_rcpf)
  return __builtin_amdgcn_rcpf(x);
#else
  float r; asm("v_rcp_f32 %0, %1" : "=v"(r) : "v"(x)); return r;
#endif
}
// a prescaled by log2e
__device__ __forceinline__ float sigmp(float a) { return rcp_(1.f + exp2_(-a)); }
// a prescaled by 2log2e
__device__ __forceinline__ float tanhp(float a) { return 1.f - 2.f * rcp_(exp2_(a) + 1.f); }

__device__ __forceinline__ f4 mfma16(h8 a, h8 b, f4 c) {
  return __builtin_amdgcn_mfma_f32_16x16x32_f16(a, b, c, 0, 0, 0);
}

__device__ __forceinline__ h8 load_w8s(const float* __restrict__ p, float sc) {
  h8 r;
#pragma unroll
  for (int j = 0; j < 8; j++) r[j] = (_Float16)(p[j] * sc);
  return r;
}

__device__ __forceinline__ unsigned packh2(float a, float b) {
  unsigned lo = (unsigned)__builtin_bit_cast(unsigned short, (_Float16)a);
  unsigned hi = (unsigned)__builtin_bit_cast(unsigned short, (_Float16)b);
  return lo | (hi << 16);
}

extern "C" __global__ void __launch_bounds__(512, 2)
weather_lstm_mfma3(const float* __restrict__ x,
                   const float* __restrict__ Wih0, const float* __restrict__ Whh0,
                   const float* __restrict__ bih0, const float* __restrict__ bhh0,
                   const float* __restrict__ Wih1, const float* __restrict__ Whh1,
                   const float* __restrict__ bih1, const float* __restrict__ bhh1,
                   const float* __restrict__ W1, const float* __restrict__ b1,
                   const float* __restrict__ W2, const float* __restrict__ b2,
                   float* __restrict__ out)
{
  __shared__ __align__(16) unsigned char smem[SMEM_TOTAL];
  const int tid  = threadIdx.x;
  const int lane = tid & 63;
  const int w    = tid >> 6;      // wave 0..7
  const int col  = lane & 15;     // sample index (B-frag n / C col)
  const int quad = lane >> 4;     // 0..3
  const int sB   = blockIdx.x * 16;

  // ---- A-frag row decode: m = lane&15 = ul*4 + g; tile T unit = w*8+2*ul+T
  const int g_  = col & 3;
  const int ul_ = col >> 2;
  const float asc = (g_ == 2) ? K2F : K1F;   // row prescale (gate g index 2)
  int arow[2];
  arow[0] = g_ * 64 + w * 8 + 2 * ul_ + 0;
  arow[1] = g_ * 64 + w * 8 + 2 * ul_ + 1;

  // ---- load + prescale weight A-frags (once) ----
  h8 a0[2][3], a1i[2][2], a1h[2][2];
#pragma unroll
  for (int T = 0; T < 2; T++) {
    const int r = arow[T];
#pragma unroll
    for (int f = 0; f < 2; f++) {
      a0[T][f]  = load_w8s(Whh0 + r * 64 + f * 32 + quad * 8, asc);
      a1i[T][f] = load_w8s(Wih1 + r * 64 + f * 32 + quad * 8, asc);
      a1h[T][f] = load_w8s(Whh1 + r * 64 + f * 32 + quad * 8, asc);
    }
    h8 xw = {};
    if (quad == 0) {
#pragma unroll
      for (int j = 0; j < 4; j++) xw[j] = (_Float16)(Wih0[r * 4 + j] * asc);
    }
    a0[T][2] = xw;
  }

  // ---- biases (prescaled): lane C rows -> unit w*8+2*quad+T, gate reg ----
  f4 bias0v[2], bias1v[2];
#pragma unroll
  for (int T = 0; T < 2; T++) {
#pragma unroll
    for (int reg = 0; reg < 4; reg++) {
      const int rr = reg * 64 + w * 8 + 2 * quad + T;
      const float bs = (reg == 2) ? K2F : K1F;
      bias0v[T][reg] = (bih0[rr] + bhh0[rr]) * bs;
      bias1v[T][reg] = (bih1[rr] + bhh1[rr]) * bs;
    }
  }

  // ---- zero LDS, stage x[0] ----
  for (int idx = tid; idx < SMEM_TOTAL / 4; idx += 512) ((int*)smem)[idx] = 0;
  __syncthreads();
  if (tid < 16) {
    f4 xv = *(const f4*)(x + ((size_t)(sB + tid) * 168 + 0) * 4);
    h4 xh;
#pragma unroll
    for (int j = 0; j < 4; j++) xh[j] = (_Float16)xv[j];
    *(h4*)(smem + H0_OFF + 0 * HBUF + tid * ROWB + 128) = xh;
  }
  __syncthreads();

  float c0[2] = {0.f, 0.f}, c1[2] = {0.f, 0.f};
  float hl[2] = {0.f, 0.f};
  const int bo = col * ROWB + quad * 16;           // B-frag byte offset
  const int wo = col * ROWB + (w * 8 + 2 * quad) * 2;  // packed h-write offset

  for (int t = 0; t < 168; t++) {
    const int pb = t & 1, nb = pb ^ 1;
    unsigned char* h0p = smem + H0_OFF + pb * HBUF;
    unsigned char* h0n = smem + H0_OFF + nb * HBUF;
    unsigned char* h1p = smem + H1_OFF + pb * HBUF;
    unsigned char* h1n = smem + H1_OFF + nb * HBUF;

    // stage x[t+1] into h0n pad (read next step after barrier2)
    if (tid < 16) {
      const int tn = (t < 167) ? t + 1 : 167;
      f4 xv = *(const f4*)(x + ((size_t)(sB + tid) * 168 + tn) * 4);
      h4 xh;
#pragma unroll
      for (int j = 0; j < 4; j++) xh[j] = (_Float16)xv[j];
      *(h4*)(h0n + tid * ROWB + 128) = xh;
    }

    // ---- reads for both pre-barrier matmuls ----
    h8 b0  = *(const h8*)(h0p + bo);         // h0_prev k 0..31
    h8 b1v = *(const h8*)(h0p + bo + 64);    // h0_prev k 32..63
    h8 b2v = *(const h8*)(h0p + bo + 128);   // [x|0]    k 64..95
    h8 q0  = *(const h8*)(h1p + bo);         // h1_prev k 0..31
    h8 q1  = *(const h8*)(h1p + bo + 64);    // h1_prev k 32..63

    // layer1 partial (Whh1 * h1_prev) — independent of barrier
    f4 l1a0 = mfma16(a1h[0][0], q0, bias1v[0]);
    f4 l1a1 = mfma16(a1h[1][0], q0, bias1v[1]);
    l1a0 = mfma16(a1h[0][1], q1, l1a0);
    l1a1 = mfma16(a1h[1][1], q1, l1a1);

    // ---------- layer 0 ----------
    f4 acc0 = mfma16(a0[0][0], b0, bias0v[0]);
    f4 acc1 = mfma16(a0[1][0], b0, bias0v[1]);
    acc0 = mfma16(a0[0][1], b1v, acc0);
    acc1 = mfma16(a0[1][1], b1v, acc1);
    acc0 = mfma16(a0[0][2], b2v, acc0);
    acc1 = mfma16(a0[1][2], b2v, acc1);

    float h0o[2];
#pragma unroll
    for (int T = 0; T < 2; T++) {
      f4 a = T ? acc1 : acc0;
      float iv = sigmp(a[0]);
      float fv = sigmp(a[1]);
      float gv = tanhp(a[2]);
      float ov = sigmp(a[3]);
      c0[T] = fv * c0[T] + iv * gv;
      h0o[T] = ov * tanhp(c0[T] * K2F);
    }
    *(unsigned*)(h0n + wo) = packh2(h0o[0], h0o[1]);
    __syncthreads();

    // ---------- layer 1 completion: Wih1 * h0_new ----------
    h8 p0 = *(const h8*)(h0n + bo);
    h8 p1 = *(const h8*)(h0n + bo + 64);
    l1a0 = mfma16(a1i[0][0], p0, l1a0);
    l1a1 = mfma16(a1i[1][0], p0, l1a1);
    l1a0 = mfma16(a1i[0][1], p1, l1a0);
    l1a1 = mfma16(a1i[1][1], p1, l1a1);

#pragma unroll
    for (int T = 0; T < 2; T++) {
      f4 a = T ? l1a1 : l1a0;
      float iv = sigmp(a[0]);
      float fv = sigmp(a[1]);
      float gv = tanhp(a[2]);
      float ov = sigmp(a[3]);
      c1[T] = fv * c1[T] + iv * gv;
      hl[T] = ov * tanhp(c1[T] * K2F);
    }
    *(unsigned*)(h1n + wo) = packh2(hl[0], hl[1]);
    __syncthreads();
  }

  // ---------- MLP head (h buffers dead; overlay) ----------
  float* fh = (float*)smem;              // [16][64] final h2, fp32
#pragma unroll
  for (int T = 0; T < 2; T++)
    fh[col * 64 + (w * 8 + 2 * quad + T)] = hl[T];
  __syncthreads();

  {
    const int u = tid & 63, grp = tid >> 6;  // 8 grps x 2 samples
    float za0 = b1[u], za1 = b1[u];
    const float* w1r = W1 + u * 64;
    const float* f0 = fh + (grp * 2 + 0) * 64;
    const float* f1 = fh + (grp * 2 + 1) * 64;
    for (int j = 0; j < 64; j++) {
      float wv = w1r[j];
      za0 += wv * f0[j];
      za1 += wv * f1[j];
    }
    float* zl = (float*)(smem + 4096);     // [16][64]
    zl[(grp * 2 + 0) * 64 + u] = fmaxf(za0, 0.f);
    zl[(grp * 2 + 1) * 64 + u] = fmaxf(za1, 0.f);
  }
  __syncthreads();

  if (tid < 192) {
    const float* zl = (const float*)(smem + 4096);
    const int s = tid / 12, o = tid - s * 12;
    float a = b2[o];
    for (int j = 0; j < 64; j++) a += W2[o * 64 + j] * zl[s * 64 + j];
    out[(sB + s) * 12 + o] = a;
  }
}

extern "C" void kernel_launch(void* const* d_in, const int* in_sizes, int n_in,
                              void* d_out, int out_size, void* d_ws, size_t ws_size,
                              hipStream_t stream) {
  (void)in_sizes; (void)n_in; (void)d_ws; (void)ws_size; (void)out_size;
  const float* x    = (const float*)d_in[0];
  const float* Wih0 = (const float*)d_in[1];
  const float* Whh0 = (const float*)d_in[2];
  const float* bih0 = (const float*)d_in[3];
  const float* bhh0 = (const float*)d_in[4];
  const float* Wih1 = (const float*)d_in[5];
  const float* Whh1 = (const float*)d_in[6];
  const float* bih1 = (const float*)d_in[7];
  const float* bhh1 = (const float*)d_in[8];
  const float* W1   = (const float*)d_in[9];
  const float* b1   = (const float*)d_in[10];
  const float* W2   = (const float*)d_in[11];
  const float* b2   = (const float*)d_in[12];

  weather_lstm_mfma3<<<dim3(256), dim3(512), 0, stream>>>(
      x, Wih0, Whh0, bih0, bhh0, Wih1, Whh1, bih1, bhh1, W1, b1, W2, b2,
      (float*)d_out);
}

// Round 4
// 226.956 us; speedup vs baseline: 3.9311x; 1.0278x over previous
//
#include <hip/hip_runtime.h>

// WeatherLSTM round 4: single-barrier software-pipelined MFMA LSTM.
//  - grid 256 x 512 thr (8 waves); block owns 16 samples; wave owns 8 units
//    (2 M-tiles, adjacent-unit mapping: tile T unit = w*8 + 2*quad + T).
//  - Iteration k computes layer0(step k) AND layer1(step k-1):
//      L0(k):  Whh0*h0(k-1) + Wih0*x(k)      [K=96, x via static LDS table]
//      L1(k-1):Wih1*h0(k-1) + Whh1*h1(k-2)   [K=128]
//    Both share the h0(k-1) ds_reads; ONE __syncthreads per iteration.
//    k=0: L1 discarded (c1/h1-write guarded). k=168: L0 discarded (x row 168
//    is a zero pad row; h0(168) write lands in a dead buffer).
//  - x table [169][16 cols][8 halves] = 43.3KB LDS, built once, coalesced.
//    Quads 1..3 read the same row as quad 0: their A-frag k64..95 is zero, so
//    any finite B value contributes 0.
//  - Activations: weights/biases prescaled by log2e (2log2e for g-gate);
//    gates share ONE rcp via common denominator ABCD; tanh(c) costs
//    1 exp2 + 1 rcp. 7 trans/unit (was 10).
//  - MFMA layouts per m89/m91/m120 (verified in R2/R3: absmax 4.9e-4).

typedef _Float16 h8 __attribute__((ext_vector_type(8)));
typedef _Float16 h4 __attribute__((ext_vector_type(4)));
typedef float f4 __attribute__((ext_vector_type(4)));

#define ROWB 208
#define HBUF (16 * ROWB)          // 3328 B per h buffer
#define XTAB_OFF 0
#define XTAB_BYTES (169 * 256)    // 43264 B (row 168 = zero pad)
#define H0_OFF XTAB_BYTES
#define H1_OFF (H0_OFF + 2 * HBUF)
#define SMEM_TOTAL (H1_OFF + 2 * HBUF)   // 56576 B

#define K1F 1.4426950408889634f   // log2(e)
#define K2F 2.8853900817779268f   // 2*log2(e)

__device__ __forceinline__ float exp2_(float x) {
#if __has_builtin(__builtin_amdgcn_exp2f)
  return __builtin_amdgcn_exp2f(x);
#else
  float r; asm("v_exp_f32 %0, %1" : "=v"(r) : "v"(x)); return r;
#endif
}
__device__ __forceinline__ float rcp_(float x) {
#if __has_builtin(__builtin_amdgcn_rcpf)
  return __builtin_amdgcn_rcpf(x);
#else
  float r; asm("v_rcp_f32 %0, %1" : "=v"(r) : "v"(x)); return r;
#endif
}

__device__ __forceinline__ f4 mfma16(h8 a, h8 b, f4 c) {
  return __builtin_amdgcn_mfma_f32_16x16x32_f16(a, b, c, 0, 0, 0);
}

__device__ __forceinline__ h8 load_w8s(const float* __restrict__ p, float sc) {
  h8 r;
#pragma unroll
  for (int j = 0; j < 8; j++) r[j] = (_Float16)(p[j] * sc);
  return r;
}

__device__ __forceinline__ unsigned packh2(float a, float b) {
  unsigned lo = (unsigned)__builtin_bit_cast(unsigned short, (_Float16)a);
  unsigned hi = (unsigned)__builtin_bit_cast(unsigned short, (_Float16)b);
  return lo | (hi << 16);
}

// a[0]=i,a[1]=f prescaled K1F; a[2]=g prescaled K2F; a[3]=o prescaled K1F.
// One rcp for all 4 gates (common denominator), one for tanh(c).
__device__ __forceinline__ void lstm_act(f4 a, float& c, float& h) {
  float Ei = exp2_(-a[0]);
  float Ef = exp2_(-a[1]);
  float Eg = exp2_(a[2]);
  float Eo = exp2_(-a[3]);
  float A = 1.f + Ei, B = 1.f + Ef, C = 1.f + Eg, D = 1.f + Eo;
  float AB = A * B, CD = C * D;
  float R = rcp_(AB * CD);
  float iv = (B * CD) * R;               // 1/A  = sigm(i)
  float fv = (A * CD) * R;               // 1/B  = sigm(f)
  float gv = 1.f - 2.f * ((AB * D) * R); // 1-2/C = tanh(g)
  float ov = (AB * C) * R;               // 1/D  = sigm(o)
  c = fv * c + iv * gv;
  float Ec = exp2_(c * K2F);
  h = ov * (1.f - 2.f * rcp_(Ec + 1.f));
}

extern "C" __global__ void __launch_bounds__(512, 1)
weather_lstm_mfma4(const float* __restrict__ x,
                   const float* __restrict__ Wih0, const float* __restrict__ Whh0,
                   const float* __restrict__ bih0, const float* __restrict__ bhh0,
                   const float* __restrict__ Wih1, const float* __restrict__ Whh1,
                   const float* __restrict__ bih1, const float* __restrict__ bhh1,
                   const float* __restrict__ W1, const float* __restrict__ b1,
                   const float* __restrict__ W2, const float* __restrict__ b2,
                   float* __restrict__ out)
{
  __shared__ __align__(16) unsigned char smem[SMEM_TOTAL];
  const int tid  = threadIdx.x;
  const int lane = tid & 63;
  const int w    = tid >> 6;      // wave 0..7
  const int col  = lane & 15;     // sample index (B-frag n / C col)
  const int quad = lane >> 4;     // 0..3
  const int sB   = blockIdx.x * 16;

  // ---- A-frag row decode: m = ul*4 + g; tile T unit = w*8 + 2*ul + T ----
  const int g_  = col & 3;
  const int ul_ = col >> 2;
  const float asc = (g_ == 2) ? K2F : K1F;
  int arow[2];
  arow[0] = g_ * 64 + w * 8 + 2 * ul_ + 0;
  arow[1] = g_ * 64 + w * 8 + 2 * ul_ + 1;

  // ---- load + prescale weight A-frags (once) ----
  h8 a0[2][3], a1i[2][2], a1h[2][2];
#pragma unroll
  for (int T = 0; T < 2; T++) {
    const int r = arow[T];
#pragma unroll
    for (int f = 0; f < 2; f++) {
      a0[T][f]  = load_w8s(Whh0 + r * 64 + f * 32 + quad * 8, asc);
      a1i[T][f] = load_w8s(Wih1 + r * 64 + f * 32 + quad * 8, asc);
      a1h[T][f] = load_w8s(Whh1 + r * 64 + f * 32 + quad * 8, asc);
    }
    h8 xw = {};
    if (quad == 0) {
#pragma unroll
      for (int j = 0; j < 4; j++) xw[j] = (_Float16)(Wih0[r * 4 + j] * asc);
    }
    a0[T][2] = xw;
  }

  // ---- biases (prescaled): lane C rows -> unit w*8+2*quad+T, gate reg ----
  f4 bias0v[2], bias1v[2];
#pragma unroll
  for (int T = 0; T < 2; T++) {
#pragma unroll
    for (int reg = 0; reg < 4; reg++) {
      const int rr = reg * 64 + w * 8 + 2 * quad + T;
      const float bs = (reg == 2) ? K2F : K1F;
      bias0v[T][reg] = (bih0[rr] + bhh0[rr]) * bs;
      bias1v[T][reg] = (bih1[rr] + bhh1[rr]) * bs;
    }
  }

  // ---- zero LDS (x table incl. pad row + h buffers), build x table ----
  for (int idx = tid; idx < SMEM_TOTAL / 4; idx += 512) ((int*)smem)[idx] = 0;
  __syncthreads();
  // fill x table: [t][col][0..3] halves; idx -> (c, t) with t fastest (coalesced)
  for (int idx = tid; idx < 16 * 168; idx += 512) {
    const int c_ = idx / 168, t_ = idx - c_ * 168;
    f4 xv = *(const f4*)(x + ((size_t)(sB + c_) * 168 + t_) * 4);
    h4 xh;
#pragma unroll
    for (int j = 0; j < 4; j++) xh[j] = (_Float16)xv[j];
    *(h4*)(smem + XTAB_OFF + t_ * 256 + c_ * 16) = xh;
  }
  __syncthreads();

  float c0[2] = {0.f, 0.f}, c1[2] = {0.f, 0.f};
  float hl[2] = {0.f, 0.f};
  const int bo = col * ROWB + quad * 16;               // B-frag byte offset
  const int wo = col * ROWB + (w * 8 + 2 * quad) * 2;  // packed h-write offset
  const unsigned char* xp = smem + XTAB_OFF + col * 16;

  for (int k = 0; k <= 168; k++) {
    const int kb = k & 1, kbn = kb ^ 1;
    const unsigned char* h0r = smem + H0_OFF + kbn * HBUF;  // h0(k-1)
    unsigned char*       h0w = smem + H0_OFF + kb  * HBUF;  // h0(k)
    const unsigned char* h1r = smem + H1_OFF + kb  * HBUF;  // h1(k-2)
    unsigned char*       h1w = smem + H1_OFF + kbn * HBUF;  // h1(k-1)

    // ---- shared ds_reads ----
    h8 b0  = *(const h8*)(h0r + bo);         // h0(k-1) k 0..31
    h8 b1v = *(const h8*)(h0r + bo + 64);    // h0(k-1) k 32..63
    h8 bx  = *(const h8*)(xp + k * 256);     // x(k) (quad0 data; others x A=0)
    h8 q0  = *(const h8*)(h1r + bo);         // h1(k-2) k 0..31
    h8 q1  = *(const h8*)(h1r + bo + 64);    // h1(k-2) k 32..63

    // ---- 14 MFMAs, 4 independent chains ----
    f4 A0 = mfma16(a0[0][0], b0, bias0v[0]);     // L0 tile0
    f4 A1 = mfma16(a0[1][0], b0, bias0v[1]);     // L0 tile1
    f4 C0 = mfma16(a1i[0][0], b0, bias1v[0]);    // L1 tile0
    f4 C1 = mfma16(a1i[1][0], b0, bias1v[1]);    // L1 tile1
    A0 = mfma16(a0[0][1], b1v, A0);
    A1 = mfma16(a0[1][1], b1v, A1);
    C0 = mfma16(a1i[0][1], b1v, C0);
    C1 = mfma16(a1i[1][1], b1v, C1);
    A0 = mfma16(a0[0][2], bx, A0);
    A1 = mfma16(a0[1][2], bx, A1);
    C0 = mfma16(a1h[0][0], q0, C0);
    C1 = mfma16(a1h[1][0], q0, C1);
    C0 = mfma16(a1h[0][1], q1, C0);
    C1 = mfma16(a1h[1][1], q1, C1);

    // ---- L0 activations (discard at k==168) ----
    if (k < 168) {
      float h0o[2];
      lstm_act(A0, c0[0], h0o[0]);
      lstm_act(A1, c0[1], h0o[1]);
      *(unsigned*)(h0w + wo) = packh2(h0o[0], h0o[1]);
    }
    // ---- L1 activations (discard at k==0) ----
    if (k > 0) {
      lstm_act(C0, c1[0], hl[0]);
      lstm_act(C1, c1[1], hl[1]);
      *(unsigned*)(h1w + wo) = packh2(hl[0], hl[1]);
    }
    __syncthreads();
  }

  // ---------- MLP head (x table region dead; overlay) ----------
  float* fh = (float*)smem;              // [16][64] final h2, fp32
#pragma unroll
  for (int T = 0; T < 2; T++)
    fh[col * 64 + (w * 8 + 2 * quad + T)] = hl[T];
  __syncthreads();

  {
    const int u = tid & 63, grp = tid >> 6;  // 8 grps x 2 samples
    float za0 = b1[u], za1 = b1[u];
    const float* w1r = W1 + u * 64;
    const float* f0 = fh + (grp * 2 + 0) * 64;
    const float* f1 = fh + (grp * 2 + 1) * 64;
    for (int j = 0; j < 64; j++) {
      float wv = w1r[j];
      za0 += wv * f0[j];
      za1 += wv * f1[j];
    }
    float* zl = (float*)(smem + 4096);     // [16][64]
    zl[(grp * 2 + 0) * 64 + u] = fmaxf(za0, 0.f);
    zl[(grp * 2 + 1) * 64 + u] = fmaxf(za1, 0.f);
  }
  __syncthreads();

  if (tid < 192) {
    const float* zl = (const float*)(smem + 4096);
    const int s = tid / 12, o = tid - s * 12;
    float a = b2[o];
    for (int j = 0; j < 64; j++) a += W2[o * 64 + j] * zl[s * 64 + j];
    out[(sB + s) * 12 + o] = a;
  }
}

extern "C" void kernel_launch(void* const* d_in, const int* in_sizes, int n_in,
                              void* d_out, int out_size, void* d_ws, size_t ws_size,
                              hipStream_t stream) {
  (void)in_sizes; (void)n_in; (void)d_ws; (void)ws_size; (void)out_size;
  const float* x    = (const float*)d_in[0];
  const float* Wih0 = (const float*)d_in[1];
  const float* Whh0 = (const float*)d_in[2];
  const float* bih0 = (const float*)d_in[3];
  const float* bhh0 = (const float*)d_in[4];
  const float* Wih1 = (const float*)d_in[5];
  const float* Whh1 = (const float*)d_in[6];
  const float* bih1 = (const float*)d_in[7];
  const float* bhh1 = (const float*)d_in[8];
  const float* W1   = (const float*)d_in[9];
  const float* b1   = (const float*)d_in[10];
  const float* W2   = (const float*)d_in[11];
  const float* b2   = (const float*)d_in[12];

  weather_lstm_mfma4<<<dim3(256), dim3(512), 0, stream>>>(
      x, Wih0, Whh0, bih0, bhh0, Wih1, Whh1, bih1, bhh1, W1, b1, W2, b2,
      (float*)d_out);
}

// Round 5
// 225.530 us; speedup vs baseline: 3.9560x; 1.0063x over previous
//
#include <hip/hip_runtime.h>

// WeatherLSTM round 5: 16-wave version of the R4 pipelined MFMA LSTM.
//  - grid 256 x 1024 thr (16 waves, 4/SIMD); block owns 16 samples.
//  - Each wave owns ONE 16-row tile = units w*4..w*4+3 (row perm ul*4+g);
//    lane holds all 4 gates of unit w*4+quad for sample col -> 1 lstm_act
//    per layer per thread. 7 MFMAs/wave/iter (3 for L0, 4 for L1).
//  - Iteration k computes L0(k) and L1(k-1) with ONE barrier (R4 scheme):
//      reads  {H0 buf kbn = h0(k-1), H1 buf kb = h1(k-2), x(k)}
//      writes {H0 buf kb = h0(k),   H1 buf kbn = h1(k-1)}   (disjoint)
//  - x table [169][16][8 halves] = 43.3KB LDS, built once (row 168 zeros;
//    quads 1..3 read quad0's row but their A-frag k64..95 is zero).
//  - Acts: weights prescaled log2e (2log2e for g); shared-rcp with fused
//    i*tanh(g) = B*D*(Eg-1)*R. 7 trans + ~19 VALU per act.
//  - MFMA layouts per m89/m91/m120 (verified R2-R4: absmax 4.9e-4).

typedef _Float16 h8 __attribute__((ext_vector_type(8)));
typedef _Float16 h4 __attribute__((ext_vector_type(4)));
typedef float f4 __attribute__((ext_vector_type(4)));

#define ROWB 208
#define HBUF (16 * ROWB)          // 3328 B per h buffer
#define XTAB_OFF 0
#define XTAB_BYTES (169 * 256)    // 43264 B (row 168 = zero pad)
#define H0_OFF XTAB_BYTES
#define H1_OFF (H0_OFF + 2 * HBUF)
#define SMEM_TOTAL (H1_OFF + 2 * HBUF)   // 56576 B

#define K1F 1.4426950408889634f   // log2(e)
#define K2F 2.8853900817779268f   // 2*log2(e)

__device__ __forceinline__ float exp2_(float x) {
#if __has_builtin(__builtin_amdgcn_exp2f)
  return __builtin_amdgcn_exp2f(x);
#else
  float r; asm("v_exp_f32 %0, %1" : "=v"(r) : "v"(x)); return r;
#endif
}
__device__ __forceinline__ float rcp_(float x) {
#if __has_builtin(__builtin_amdgcn_rcpf)
  return __builtin_amdgcn_rcpf(x);
#else
  float r; asm("v_rcp_f32 %0, %1" : "=v"(r) : "v"(x)); return r;
#endif
}

__device__ __forceinline__ f4 mfma16(h8 a, h8 b, f4 c) {
  return __builtin_amdgcn_mfma_f32_16x16x32_f16(a, b, c, 0, 0, 0);
}

__device__ __forceinline__ h8 load_w8s(const float* __restrict__ p, float sc) {
  h8 r;
#pragma unroll
  for (int j = 0; j < 8; j++) r[j] = (_Float16)(p[j] * sc);
  return r;
}

// a[0]=i,a[1]=f,a[3]=o prescaled K1F; a[2]=g prescaled K2F.
// sigm(i)*tanh(g) = (Eg-1)/(A*C) = B*D*(Eg-1)*R with R=1/(ABCD).
__device__ __forceinline__ void lstm_act(f4 a, float& c, float& h) {
  float Ei = exp2_(-a[0]);
  float Ef = exp2_(-a[1]);
  float Eg = exp2_(a[2]);
  float Eo = exp2_(-a[3]);
  float A = 1.f + Ei, B = 1.f + Ef, C = 1.f + Eg, D = 1.f + Eo;
  float AB = A * B, CD = C * D, BD = B * D;
  float R  = rcp_(AB * CD);
  float fv = (A * CD) * R;               // sigm(f)
  float ig = (BD * (Eg - 1.f)) * R;      // sigm(i)*tanh(g)
  float ov = (AB * C) * R;               // sigm(o)
  c = fv * c + ig;
  float r2 = rcp_(exp2_(c * K2F) + 1.f);
  h = ov * (1.f - 2.f * r2);
}

extern "C" __global__ void __launch_bounds__(1024, 4)
weather_lstm_mfma5(const float* __restrict__ x,
                   const float* __restrict__ Wih0, const float* __restrict__ Whh0,
                   const float* __restrict__ bih0, const float* __restrict__ bhh0,
                   const float* __restrict__ Wih1, const float* __restrict__ Whh1,
                   const float* __restrict__ bih1, const float* __restrict__ bhh1,
                   const float* __restrict__ W1, const float* __restrict__ b1,
                   const float* __restrict__ W2, const float* __restrict__ b2,
                   float* __restrict__ out)
{
  __shared__ __align__(16) unsigned char smem[SMEM_TOTAL];
  const int tid  = threadIdx.x;
  const int lane = tid & 63;
  const int w    = tid >> 6;      // wave 0..15 -> units w*4..w*4+3
  const int col  = lane & 15;     // sample index (B-frag n / C col)
  const int quad = lane >> 4;     // 0..3
  const int sB   = blockIdx.x * 16;

  // ---- A-frag row decode: m = lane&15 = ul*4 + g; unit = w*4 + ul ----
  const int g_  = col & 3;
  const int ul_ = col >> 2;
  const float asc = (g_ == 2) ? K2F : K1F;
  const int r = g_ * 64 + w * 4 + ul_;

  // ---- load + prescale weight A-frags (once) ----
  h8 a0[3], a1i[2], a1h[2];
#pragma unroll
  for (int f = 0; f < 2; f++) {
    a0[f]  = load_w8s(Whh0 + r * 64 + f * 32 + quad * 8, asc);
    a1i[f] = load_w8s(Wih1 + r * 64 + f * 32 + quad * 8, asc);
    a1h[f] = load_w8s(Whh1 + r * 64 + f * 32 + quad * 8, asc);
  }
  {
    h8 xw = {};
    if (quad == 0) {
#pragma unroll
      for (int j = 0; j < 4; j++) xw[j] = (_Float16)(Wih0[r * 4 + j] * asc);
    }
    a0[2] = xw;
  }

  // ---- biases (prescaled): lane C rows reg -> gate reg, unit w*4+quad ----
  f4 bias0v, bias1v;
#pragma unroll
  for (int reg = 0; reg < 4; reg++) {
    const int rr = reg * 64 + w * 4 + quad;
    const float bs = (reg == 2) ? K2F : K1F;
    bias0v[reg] = (bih0[rr] + bhh0[rr]) * bs;
    bias1v[reg] = (bih1[rr] + bhh1[rr]) * bs;
  }

  // ---- zero LDS, build x table ----
  for (int idx = tid; idx < SMEM_TOTAL / 4; idx += 1024) ((int*)smem)[idx] = 0;
  __syncthreads();
  for (int idx = tid; idx < 16 * 168; idx += 1024) {
    const int c_ = idx / 168, t_ = idx - c_ * 168;
    f4 xv = *(const f4*)(x + ((size_t)(sB + c_) * 168 + t_) * 4);
    h4 xh;
#pragma unroll
    for (int j = 0; j < 4; j++) xh[j] = (_Float16)xv[j];
    *(h4*)(smem + XTAB_OFF + t_ * 256 + c_ * 16) = xh;
  }
  __syncthreads();

  float c0 = 0.f, c1 = 0.f, hl = 0.f;
  const int bo = col * ROWB + quad * 16;                // B-frag byte offset
  const int wo = col * ROWB + (w * 4 + quad) * 2;       // h-write byte offset
  const unsigned char* xp = smem + XTAB_OFF + col * 16;

  for (int k = 0; k <= 168; k++) {
    const int kb = k & 1, kbn = kb ^ 1;
    const unsigned char* h0r = smem + H0_OFF + kbn * HBUF;  // h0(k-1)
    unsigned char*       h0w = smem + H0_OFF + kb  * HBUF;  // h0(k)
    const unsigned char* h1r = smem + H1_OFF + kb  * HBUF;  // h1(k-2)
    unsigned char*       h1w = smem + H1_OFF + kbn * HBUF;  // h1(k-1)

    // ---- shared ds_reads ----
    h8 b0  = *(const h8*)(h0r + bo);         // h0(k-1) k 0..31
    h8 b1v = *(const h8*)(h0r + bo + 64);    // h0(k-1) k 32..63
    h8 bx  = *(const h8*)(xp + k * 256);     // x(k) (quad0 data; others A=0)
    h8 q0  = *(const h8*)(h1r + bo);         // h1(k-2) k 0..31
    h8 q1  = *(const h8*)(h1r + bo + 64);    // h1(k-2) k 32..63

    // ---- 7 MFMAs, 2 chains ----
    f4 A0 = mfma16(a0[0], b0, bias0v);       // L0
    f4 C0 = mfma16(a1i[0], b0, bias1v);      // L1
    A0 = mfma16(a0[1], b1v, A0);
    C0 = mfma16(a1i[1], b1v, C0);
    A0 = mfma16(a0[2], bx, A0);
    C0 = mfma16(a1h[0], q0, C0);
    C0 = mfma16(a1h[1], q1, C0);

    // ---- L0 activations (discard at k==168) ----
    if (k < 168) {
      float h0o;
      lstm_act(A0, c0, h0o);
      *(_Float16*)(h0w + wo) = (_Float16)h0o;
    }
    // ---- L1 activations (discard at k==0) ----
    if (k > 0) {
      lstm_act(C0, c1, hl);
      *(_Float16*)(h1w + wo) = (_Float16)hl;
    }
    __syncthreads();
  }

  // ---------- MLP head (x table region dead; overlay) ----------
  float* fh = (float*)smem;              // [16][64] final h2, fp32
  fh[col * 64 + (w * 4 + quad)] = hl;
  __syncthreads();

  {
    const int u = tid & 63, grp = tid >> 6;  // 16 grps x 1 sample
    float za = b1[u];
    const float* w1r = W1 + u * 64;
    const float* f0 = fh + grp * 64;
    for (int j = 0; j < 64; j++) za += w1r[j] * f0[j];
    float* zl = (float*)(smem + 4096);     // [16][64]
    zl[grp * 64 + u] = fmaxf(za, 0.f);
  }
  __syncthreads();

  if (tid < 192) {
    const float* zl = (const float*)(smem + 4096);
    const int s = tid / 12, o = tid - s * 12;
    float a = b2[o];
    for (int j = 0; j < 64; j++) a += W2[o * 64 + j] * zl[s * 64 + j];
    out[(sB + s) * 12 + o] = a;
  }
}

extern "C" void kernel_launch(void* const* d_in, const int* in_sizes, int n_in,
                              void* d_out, int out_size, void* d_ws, size_t ws_size,
                              hipStream_t stream) {
  (void)in_sizes; (void)n_in; (void)d_ws; (void)ws_size; (void)out_size;
  const float* x    = (const float*)d_in[0];
  const float* Wih0 = (const float*)d_in[1];
  const float* Whh0 = (const float*)d_in[2];
  const float* bih0 = (const float*)d_in[3];
  const float* bhh0 = (const float*)d_in[4];
  const float* Wih1 = (const float*)d_in[5];
  const float* Whh1 = (const float*)d_in[6];
  const float* bih1 = (const float*)d_in[7];
  const float* bhh1 = (const float*)d_in[8];
  const float* W1   = (const float*)d_in[9];
  const float* b1   = (const float*)d_in[10];
  const float* W2   = (const float*)d_in[11];
  const float* b2   = (const float*)d_in[12];

  weather_lstm_mfma5<<<dim3(256), dim3(1024), 0, stream>>>(
      x, Wih0, Whh0, bih0, bhh0, Wih1, Whh1, bih1, bhh1, W1, b1, W2, b2,
      (float*)d_out);
}